// Round 1
// baseline (373.153 us; speedup 1.0000x reference)
//
#include <hip/hip_runtime.h>
#include <hip/hip_bf16.h>

// Problem dims (fixed by setup_inputs): B=4, S=2048, DIN=4096, DOUT=4096, GS=32
#define DIN   4096
#define DOUT  4096
#define MROWS 8192            // B*S
#define GSIZE 32
#define NGPR  (DIN / GSIZE)   // groups per row = 128
#define NG_ACT (MROWS * NGPR) // 1048576
#define NG_W   (DOUT * NGPR)  // 524288

typedef __bf16 bf16_t;
typedef __attribute__((ext_vector_type(8))) __bf16 bf16x8;
typedef __attribute__((ext_vector_type(4))) float f32x4;

typedef const __attribute__((address_space(1))) void* gptr_t;
typedef __attribute__((address_space(3))) void* lptr_t;

// floor(log2(max(a,1))) grid rounding to the FP4 E2M1 set {0,±0.5,1,1.5,2,3,4,6}
__device__ __forceinline__ float fp4_round(float y) {
  float a  = __builtin_fabsf(y);
  float am = fmaxf(a, 1.0f);
  int   e  = (int)((__float_as_uint(am) >> 23) & 255u) - 127;  // floor(log2(max(a,1)))
  float step = __uint_as_float((unsigned)(e - 1 + 127) << 23); // 2^(e-1): 0.5, 1, 2
  float q = rintf(a / step) * step;  // RNE, matches jnp.round
  q = fminf(q, 6.0f);
  return copysignf(q, y);
}

// ---------------- activation quant: one thread per group of 32 ----------------
__global__ __launch_bounds__(256) void act_quant(const float* __restrict__ x,
                                                 bf16_t* __restrict__ xq,
                                                 float* __restrict__ exps_out) {
  int g = blockIdx.x * 256 + threadIdx.x;
  const float4* xp = reinterpret_cast<const float4*>(x) + (size_t)g * 8;
  float v[32];
  float amax = 0.f;
#pragma unroll
  for (int i = 0; i < 8; ++i) {
    float4 t = xp[i];
    v[4*i+0] = t.x; v[4*i+1] = t.y; v[4*i+2] = t.z; v[4*i+3] = t.w;
    amax = fmaxf(amax, fmaxf(fmaxf(__builtin_fabsf(t.x), __builtin_fabsf(t.y)),
                             fmaxf(__builtin_fabsf(t.z), __builtin_fabsf(t.w))));
  }
  float exps = 0.f;
  if (amax > 0.f) {
    float am = fmaxf(amax, 1e-30f);
    exps = (float)((int)((__float_as_uint(am) >> 23) & 255u) - 129);  // floor(log2)-2
  }
  float scale = __uint_as_float((unsigned)((int)exps + 127) << 23);   // 2^exps (exact)
  float inv   = __uint_as_float((unsigned)(127 - (int)exps) << 23);   // 2^-exps (exact)
  bf16x8 hv[4];
#pragma unroll
  for (int i = 0; i < 32; ++i) {
    float q = fp4_round(v[i] * inv) * scale;  // exact: pow2 scaling both ways
    hv[i >> 3][i & 7] = (bf16_t)q;            // exact in bf16 (<=2 mantissa bits * 2^e)
  }
  bf16x8* dst = reinterpret_cast<bf16x8*>(xq + (size_t)g * 32);
#pragma unroll
  for (int i = 0; i < 4; ++i) dst[i] = hv[i];
  exps_out[g] = exps;
}

// ---------------- weight quant with (1+eps_eff) scale ----------------
__global__ __launch_bounds__(256) void w_quant(const float* __restrict__ w,
                                               const float* __restrict__ eps,
                                               const float* __restrict__ adv,
                                               bf16_t* __restrict__ wq,
                                               float* __restrict__ eps_eff_out,
                                               float* __restrict__ w_exps_out) {
  int g = blockIdx.x * 256 + threadIdx.x;
  float ee = eps[g] + adv[g];
  eps_eff_out[g] = ee;
  const float4* wp = reinterpret_cast<const float4*>(w) + (size_t)g * 8;
  float v[32];
  float amax = 0.f;
#pragma unroll
  for (int i = 0; i < 8; ++i) {
    float4 t = wp[i];
    v[4*i+0] = t.x; v[4*i+1] = t.y; v[4*i+2] = t.z; v[4*i+3] = t.w;
    amax = fmaxf(amax, fmaxf(fmaxf(__builtin_fabsf(t.x), __builtin_fabsf(t.y)),
                             fmaxf(__builtin_fabsf(t.z), __builtin_fabsf(t.w))));
  }
  float exps = 0.f;
  if (amax > 0.f) {
    float am = fmaxf(amax, 1e-30f);
    exps = (float)((int)((__float_as_uint(am) >> 23) & 255u) - 129);
  }
  w_exps_out[g] = exps;
  float p2   = __uint_as_float((unsigned)((int)exps + 127) << 23);  // 2^exps
  float scale = p2 * (1.0f + ee);                                   // matches reference order
  bf16x8 hv[4];
#pragma unroll
  for (int i = 0; i < 32; ++i) {
    float q = fp4_round(v[i] / scale) * scale;  // IEEE div, matches reference
    hv[i >> 3][i & 7] = (bf16_t)q;              // only bf16-rounding error source
  }
  bf16x8* dst = reinterpret_cast<bf16x8*>(wq + (size_t)g * 32);
#pragma unroll
  for (int i = 0; i < 4; ++i) dst[i] = hv[i];
}

// ---------------- bf16 GEMM: C[M,N] = A[M,K] * B[N,K]^T + bias ----------------
// m97 structure: 128x128 tile, BK=32, 4 waves (2x2), 4x4 acc of 16x16x32 MFMA,
// global_load_lds width=16 staging, 2-barrier K-loop.
#define BK 32
__global__ __launch_bounds__(256) void gemm_bt(const bf16_t* __restrict__ A,
                                               const bf16_t* __restrict__ B,
                                               const float* __restrict__ bias,
                                               float* __restrict__ C) {
  __shared__ bf16_t As[128 * BK];
  __shared__ bf16_t Bs[128 * BK];
  const int tid  = threadIdx.x;
  const int wave = tid >> 6;
  const int lane = tid & 63;
  const int tm0  = blockIdx.y * 128;
  const int tn0  = blockIdx.x * 128;
  const int wr   = wave >> 1;  // 0..1
  const int wc   = wave & 1;   // 0..1

  const int lrow = lane >> 2;        // 0..15 (row within 16-row staging slab)
  const int lcol = (lane & 3) * 8;   // 0,8,16,24 (bf16 elements)

  f32x4 acc[4][4] = {};

  const int afrag_off = (wr * 64 + (lane & 15)) * BK + (lane >> 4) * 8;
  const int bfrag_off = (wc * 64 + (lane & 15)) * BK + (lane >> 4) * 8;

  for (int kt = 0; kt < DIN / BK; ++kt) {
    // ---- stage A and B tiles (each wave: 2 issues x 16 rows x 64B) ----
#pragma unroll
    for (int i = 0; i < 2; ++i) {
      const int r0 = wave * 32 + i * 16;  // wave-uniform
      const bf16_t* ga = A + (size_t)(tm0 + r0 + lrow) * DIN + kt * BK + lcol;
      __builtin_amdgcn_global_load_lds((gptr_t)ga, (lptr_t)(As + r0 * BK), 16, 0, 0);
      const bf16_t* gb = B + (size_t)(tn0 + r0 + lrow) * DIN + kt * BK + lcol;
      __builtin_amdgcn_global_load_lds((gptr_t)gb, (lptr_t)(Bs + r0 * BK), 16, 0, 0);
    }
    asm volatile("s_waitcnt vmcnt(0)" ::: "memory");
    __syncthreads();

    // ---- fragments: 8 contiguous bf16 along K per lane ----
    bf16x8 af[4], bfr[4];
#pragma unroll
    for (int t = 0; t < 4; ++t) {
      af[t]  = *reinterpret_cast<const bf16x8*>(&As[t * 16 * BK + afrag_off]);
      bfr[t] = *reinterpret_cast<const bf16x8*>(&Bs[t * 16 * BK + bfrag_off]);
    }
#pragma unroll
    for (int am = 0; am < 4; ++am)
#pragma unroll
      for (int bn = 0; bn < 4; ++bn)
        acc[am][bn] = __builtin_amdgcn_mfma_f32_16x16x32_bf16(af[am], bfr[bn], acc[am][bn], 0, 0, 0);
    __syncthreads();
  }

  // ---- epilogue: D row=(lane>>4)*4+reg, col=lane&15 (m89-verified) ----
  const int row_base = tm0 + wr * 64 + ((lane >> 4) << 2);
  const int col_base = tn0 + wc * 64 + (lane & 15);
#pragma unroll
  for (int bn = 0; bn < 4; ++bn) {
    float bv = bias[col_base + bn * 16];
#pragma unroll
    for (int am = 0; am < 4; ++am) {
#pragma unroll
      for (int j = 0; j < 4; ++j) {
        C[(size_t)(row_base + am * 16 + j) * DOUT + col_base + bn * 16] = acc[am][bn][j] + bv;
      }
    }
  }
}

extern "C" void kernel_launch(void* const* d_in, const int* in_sizes, int n_in,
                              void* d_out, int out_size, void* d_ws, size_t ws_size,
                              hipStream_t stream) {
  const float* x    = (const float*)d_in[0];  // (4,2048,4096)
  const float* adv  = (const float*)d_in[1];  // (4096,128)
  const float* wfp  = (const float*)d_in[2];  // (4096,4096)
  const float* bias = (const float*)d_in[3];  // (4096,)
  const float* eps  = (const float*)d_in[4];  // (4096,128)

  float* out      = (float*)d_out;                    // 33554432
  float* eps_eff  = out + (size_t)MROWS * DOUT;       // 524288
  float* w_exps   = eps_eff + NG_W;                   // 524288
  float* act_exps = w_exps + NG_W;                    // 1048576

  bf16_t* xq = (bf16_t*)d_ws;                          // 67.1 MB
  bf16_t* wq = (bf16_t*)d_ws + (size_t)MROWS * DIN;    // +33.6 MB (needs ~100.7 MB ws)

  act_quant<<<NG_ACT / 256, 256, 0, stream>>>(x, xq, act_exps);
  w_quant<<<NG_W / 256, 256, 0, stream>>>(wfp, eps, adv, wq, eps_eff, w_exps);
  gemm_bt<<<dim3(DOUT / 128, MROWS / 128), 256, 0, stream>>>(xq, wq, bias, out);
}